// Round 4
// baseline (238.331 us; speedup 1.0000x reference)
//
#include <hip/hip_runtime.h>

#define BATCH 32
#define NAG   4096
#define FDIM  128
#define LREC  200      // L*DH floats per (b,n) record in hist_feat
#define KSEL  8

// ---------------------------------------------------------------------------
// Kernel 1: one wave handles EIGHT agents. Group g = lane>>3 owns agent
// n0+g; sub = lane&7 indexes 4 float4 chunks (8 lanes x 16B = one 128B line
// per group per chunk). hf velocity loads are hoisted to the TOP (every lane
// loads its group's 16B, L1-broadcast) so their latency overlaps the row
// loads. After the 3-step butterfly, every lane of group g holds the sums,
// so the epilogue is computed branch-free on all 64 lanes (one agent per
// group, 8 redundant lanes each); only the store is predicated on sub==0.
// No redistribution shuffles, no exec-masked load tail.
// scores[b*4096 + n]; slot n==0 forced to +inf.
// ---------------------------------------------------------------------------
__global__ __launch_bounds__(256) void score_kernel(
    const float* __restrict__ x,     // (B, N, FDIM)
    const float* __restrict__ hf,    // (B, N, L, DH)
    const float* __restrict__ he,    // (B, N, FDIM)
    float* __restrict__ scores)      // (B, N)
{
    const int tid  = threadIdx.x;
    const int wave = (blockIdx.x * 256 + tid) >> 6;   // 16384 waves total
    const int lane = tid & 63;
    const int g    = lane >> 3;      // which of 8 agents
    const int sub  = lane & 7;       // chunk lane within agent

    const int b  = wave >> 9;        // 512 waves per batch
    const int n0 = (wave & 511) << 3;
    const int n  = n0 + g;

    const size_t base = (size_t)(b << 12);

    // ---- velocity-history loads FIRST (latency overlaps the row loads) ----
    const float* hg = hf + (base + n) * LREC + 192;   // this group's agent
    const float* h0 = hf + base * LREC + 192;         // center agent
    const float2 hn0 = *(const float2*)(hg);
    const float2 hn1 = *(const float2*)(hg + 4);
    const float2 h00 = *(const float2*)(h0);
    const float2 h01 = *(const float2*)(h0 + 4);

    const float* xn = x  + (base + n) * FDIM;
    const float* xc = x  + base * FDIM;
    const float* en = he + (base + n) * FDIM;
    const float* ec = he + base * FDIM;

    float dist2 = 0.f, dotv = 0.f, nn = 0.f, cc = 0.f;
    #pragma unroll
    for (int t = 0; t < 4; ++t) {
        const int d = t * 32 + sub * 4;
        const float4 a = *(const float4*)(xn + d);
        const float4 c = *(const float4*)(xc + d);
        const float4 e = *(const float4*)(en + d);
        const float4 f = *(const float4*)(ec + d);
        float dx;
        dx = a.x - c.x; dist2 += dx * dx;
        dx = a.y - c.y; dist2 += dx * dx;
        dx = a.z - c.z; dist2 += dx * dx;
        dx = a.w - c.w; dist2 += dx * dx;
        dotv += e.x * f.x + e.y * f.y + e.z * f.z + e.w * f.w;
        nn   += e.x * e.x + e.y * e.y + e.z * e.z + e.w * e.w;
        cc   += f.x * f.x + f.y * f.y + f.z * f.z + f.w * f.w;
    }

    #pragma unroll
    for (int m = 4; m; m >>= 1) {     // reduce within each 8-lane group
        dist2 += __shfl_xor(dist2, m, 64);
        dotv  += __shfl_xor(dotv,  m, 64);
        nn    += __shfl_xor(nn,    m, 64);
        cc    += __shfl_xor(cc,    m, 64);
    }

    // ---- epilogue: branch-free on all lanes (8 redundant lanes/agent) ----
    const float dist = sqrtf(dist2);
    const float traj = dotv / (fmaxf(sqrtf(nn), 1e-8f) * fmaxf(sqrtf(cc), 1e-8f));

    const float dnx = hn1.x - hn0.x, dny = hn1.y - hn0.y;
    const float d0x = h01.x - h00.x, d0y = h01.y - h00.y;

    const float n0v = fmaxf(sqrtf(d0x * d0x + d0y * d0y), 1e-12f);
    const float cdx = d0x / n0v + 1e-8f, cdy = d0y / n0v + 1e-8f;
    const float nn2 = fmaxf(sqrtf(dnx * dnx + dny * dny), 1e-12f);
    const float odx = dnx / nn2 + 1e-8f, ody = dny / nn2 + 1e-8f;

    const float num = odx * cdx + ody * cdy;
    const float den = fmaxf(sqrtf(odx * odx + ody * ody), 1e-8f) *
                      fmaxf(sqrtf(cdx * cdx + cdy * cdy), 1e-8f);
    const float vel = num / den;

    const float score = 0.3f * dist
                      + 0.5f * (1.0f - fmaxf(vel,  0.0f))
                      + 0.4f * (1.0f - fmaxf(traj, 0.0f));

    if (sub == 0)
        scores[base + n] = (n == 0) ? 1e30f : score;
}

// ---------------------------------------------------------------------------
// Kernel 2: one block per batch. Scores cached in 16 registers/thread;
// 8 rounds of iterative arg-min (tie-break lower index = jax.lax.top_k),
// then gather rows + write indices (as float).
// ---------------------------------------------------------------------------
__global__ __launch_bounds__(256) void topk_gather_kernel(
    const float* __restrict__ scores,
    const float* __restrict__ x,
    float* __restrict__ out)
{
    const int b   = blockIdx.x;
    const int tid = threadIdx.x;

    float v[16];
    #pragma unroll
    for (int j = 0; j < 16; ++j)
        v[j] = scores[(size_t)(b << 12) + (j << 8) + tid];  // i = j*256 + tid

    __shared__ float red_s[4];
    __shared__ int   red_i[4];
    __shared__ int   sel[KSEL];

    for (int r = 0; r < KSEL; ++r) {
        float best = 1e30f;
        int   bi   = 0x7fffffff;
        #pragma unroll
        for (int j = 0; j < 16; ++j) {
            const int   i  = (j << 8) + tid;
            const float vv = v[j];
            if (vv < best || (vv == best && i < bi)) { best = vv; bi = i; }
        }
        #pragma unroll
        for (int m = 32; m; m >>= 1) {
            const float ov = __shfl_xor(best, m, 64);
            const int   oi = __shfl_xor(bi,   m, 64);
            if (ov < best || (ov == best && oi < bi)) { best = ov; bi = oi; }
        }
        if ((tid & 63) == 0) { red_s[tid >> 6] = best; red_i[tid >> 6] = bi; }
        __syncthreads();
        if (tid == 0) {
            float bb = red_s[0]; int ii = red_i[0];
            #pragma unroll
            for (int w = 1; w < 4; ++w)
                if (red_s[w] < bb || (red_s[w] == bb && red_i[w] < ii)) {
                    bb = red_s[w]; ii = red_i[w];
                }
            sel[r] = ii;
        }
        __syncthreads();
        const int w = sel[r];
        if ((w & 255) == tid) v[w >> 8] = 1e30f;   // exclude winner locally
    }

    // gather 8 rows x 128 floats
    for (int e2 = tid; e2 < KSEL * FDIM; e2 += 256) {
        const int j = e2 >> 7;
        const int d = e2 & 127;
        const int n = sel[j];
        out[((size_t)b * KSEL + j) * FDIM + d] = x[((size_t)(b << 12) + n) * FDIM + d];
    }
    if (tid < KSEL)
        out[(size_t)BATCH * KSEL * FDIM + b * KSEL + tid] = (float)(sel[tid] - 1);
}

extern "C" void kernel_launch(void* const* d_in, const int* in_sizes, int n_in,
                              void* d_out, int out_size, void* d_ws, size_t ws_size,
                              hipStream_t stream) {
    const float* x  = (const float*)d_in[0];   // (B, N, FDIM)
    const float* hf = (const float*)d_in[1];   // (B, N, L, DH)
    const float* he = (const float*)d_in[2];   // (B, N, FDIM)
    float* out = (float*)d_out;
    float* scores = (float*)d_ws;              // B*N floats = 512 KB

    // Phase 1: 32 batches x 512 agent-octets = 16384 waves, 4 waves/block
    const int blocks1 = (BATCH * (NAG / 8) * 64) / 256;   // 4096
    score_kernel<<<blocks1, 256, 0, stream>>>(x, hf, he, scores);

    // Phase 2: one block per batch
    topk_gather_kernel<<<BATCH, 256, 0, stream>>>(scores, x, out);
}

// Round 6
// 216.417 us; speedup vs baseline: 1.1013x; 1.1013x over previous
//
#include <hip/hip_runtime.h>

#define BATCH 32
#define NAG   4096
#define FDIM  128
#define LREC  200      // L*DH floats per (b,n) record in hist_feat
#define KSEL  8

typedef float vf2 __attribute__((ext_vector_type(2)));
typedef float vf4 __attribute__((ext_vector_type(4)));

// ---------------------------------------------------------------------------
// Kernel 1: one wave handles EIGHT agents. Group g = lane>>3 owns agent
// n0+g; sub = lane&7 indexes 4 float4 chunks (8 lanes x 16B = one 128B line
// per group per chunk). Streamed, never-reused data (agent rows of x/he and
// the hf velocity slice) is loaded NONTEMPORAL (nt flag) so it doesn't
// thrash L2, which is full of dirty lines from the harness's 419MB poison
// fill. Center rows stay cached (reused by every wave of the batch).
// hf loads hoisted to the top; epilogue branch-free on all 64 lanes.
// scores[b*4096 + n]; slot n==0 forced to +inf.
// ---------------------------------------------------------------------------
__global__ __launch_bounds__(256) void score_kernel(
    const float* __restrict__ x,     // (B, N, FDIM)
    const float* __restrict__ hf,    // (B, N, L, DH)
    const float* __restrict__ he,    // (B, N, FDIM)
    float* __restrict__ scores)      // (B, N)
{
    const int tid  = threadIdx.x;
    const int wave = (blockIdx.x * 256 + tid) >> 6;   // 16384 waves total
    const int lane = tid & 63;
    const int g    = lane >> 3;      // which of 8 agents
    const int sub  = lane & 7;       // chunk lane within agent

    const int b  = wave >> 9;        // 512 waves per batch
    const int n0 = (wave & 511) << 3;
    const int n  = n0 + g;

    const size_t base = (size_t)(b << 12);

    // ---- velocity-history loads FIRST (latency overlaps the row loads) ----
    const float* hg = hf + (base + n) * LREC + 192;   // this group's agent
    const float* h0 = hf + base * LREC + 192;         // center agent
    const vf2 hn0 = __builtin_nontemporal_load((const vf2*)(hg));
    const vf2 hn1 = __builtin_nontemporal_load((const vf2*)(hg + 4));
    const vf2 h00 = *(const vf2*)(h0);
    const vf2 h01 = *(const vf2*)(h0 + 4);

    const float* xn = x  + (base + n) * FDIM;
    const float* xc = x  + base * FDIM;
    const float* en = he + (base + n) * FDIM;
    const float* ec = he + base * FDIM;

    float dist2 = 0.f, dotv = 0.f, nn = 0.f, cc = 0.f;
    #pragma unroll
    for (int t = 0; t < 4; ++t) {
        const int d = t * 32 + sub * 4;
        const vf4 a = __builtin_nontemporal_load((const vf4*)(xn + d));
        const vf4 e = __builtin_nontemporal_load((const vf4*)(en + d));
        const vf4 c = *(const vf4*)(xc + d);
        const vf4 f = *(const vf4*)(ec + d);
        float dx;
        dx = a.x - c.x; dist2 += dx * dx;
        dx = a.y - c.y; dist2 += dx * dx;
        dx = a.z - c.z; dist2 += dx * dx;
        dx = a.w - c.w; dist2 += dx * dx;
        dotv += e.x * f.x + e.y * f.y + e.z * f.z + e.w * f.w;
        nn   += e.x * e.x + e.y * e.y + e.z * e.z + e.w * e.w;
        cc   += f.x * f.x + f.y * f.y + f.z * f.z + f.w * f.w;
    }

    #pragma unroll
    for (int m = 4; m; m >>= 1) {     // reduce within each 8-lane group
        dist2 += __shfl_xor(dist2, m, 64);
        dotv  += __shfl_xor(dotv,  m, 64);
        nn    += __shfl_xor(nn,    m, 64);
        cc    += __shfl_xor(cc,    m, 64);
    }

    // ---- epilogue: branch-free on all lanes (8 redundant lanes/agent) ----
    const float dist = sqrtf(dist2);
    const float traj = dotv / (fmaxf(sqrtf(nn), 1e-8f) * fmaxf(sqrtf(cc), 1e-8f));

    const float dnx = hn1.x - hn0.x, dny = hn1.y - hn0.y;
    const float d0x = h01.x - h00.x, d0y = h01.y - h00.y;

    const float n0v = fmaxf(sqrtf(d0x * d0x + d0y * d0y), 1e-12f);
    const float cdx = d0x / n0v + 1e-8f, cdy = d0y / n0v + 1e-8f;
    const float nn2 = fmaxf(sqrtf(dnx * dnx + dny * dny), 1e-12f);
    const float odx = dnx / nn2 + 1e-8f, ody = dny / nn2 + 1e-8f;

    const float num = odx * cdx + ody * cdy;
    const float den = fmaxf(sqrtf(odx * odx + ody * ody), 1e-8f) *
                      fmaxf(sqrtf(cdx * cdx + cdy * cdy), 1e-8f);
    const float vel = num / den;

    const float score = 0.3f * dist
                      + 0.5f * (1.0f - fmaxf(vel,  0.0f))
                      + 0.4f * (1.0f - fmaxf(traj, 0.0f));

    if (sub == 0)
        scores[base + n] = (n == 0) ? 1e30f : score;
}

// ---------------------------------------------------------------------------
// Kernel 2: one block per batch. Scores cached in 16 registers/thread.
// Scores are all >= 0, so IEEE float bits order as uint32; pack
// key = (score_bits<<32)|idx -> u64 min gives arg-min with lower-index
// tie-break (== jax.lax.top_k semantics) in ONE min per butterfly step.
// ---------------------------------------------------------------------------
__global__ __launch_bounds__(256) void topk_gather_kernel(
    const float* __restrict__ scores,
    const float* __restrict__ x,
    float* __restrict__ out)
{
    const int b   = blockIdx.x;
    const int tid = threadIdx.x;

    float v[16];
    #pragma unroll
    for (int j = 0; j < 16; ++j)
        v[j] = scores[(size_t)(b << 12) + (j << 8) + tid];  // i = j*256 + tid

    __shared__ unsigned long long red[4];
    __shared__ int sel[KSEL];

    for (int r = 0; r < KSEL; ++r) {
        unsigned long long k = 0xffffffffffffffffULL;
        #pragma unroll
        for (int j = 0; j < 16; ++j) {
            const unsigned long long kk =
                ((unsigned long long)__float_as_uint(v[j]) << 32) |
                (unsigned int)((j << 8) + tid);
            k = (kk < k) ? kk : k;
        }
        #pragma unroll
        for (int m = 32; m; m >>= 1) {
            const unsigned long long ok = __shfl_xor(k, m, 64);
            k = (ok < k) ? ok : k;
        }
        if ((tid & 63) == 0) red[tid >> 6] = k;
        __syncthreads();
        if (tid == 0) {
            unsigned long long kk = red[0];
            #pragma unroll
            for (int w = 1; w < 4; ++w) kk = (red[w] < kk) ? red[w] : kk;
            sel[r] = (int)(kk & 0xffffffffu);
        }
        __syncthreads();
        const int w = sel[r];
        if ((w & 255) == tid) v[w >> 8] = 1e30f;   // exclude winner locally
    }

    // gather 8 rows x 128 floats
    for (int e2 = tid; e2 < KSEL * FDIM; e2 += 256) {
        const int j = e2 >> 7;
        const int d = e2 & 127;
        const int n = sel[j];
        out[((size_t)b * KSEL + j) * FDIM + d] = x[((size_t)(b << 12) + n) * FDIM + d];
    }
    if (tid < KSEL)
        out[(size_t)BATCH * KSEL * FDIM + b * KSEL + tid] = (float)(sel[tid] - 1);
}

extern "C" void kernel_launch(void* const* d_in, const int* in_sizes, int n_in,
                              void* d_out, int out_size, void* d_ws, size_t ws_size,
                              hipStream_t stream) {
    const float* x  = (const float*)d_in[0];   // (B, N, FDIM)
    const float* hf = (const float*)d_in[1];   // (B, N, L, DH)
    const float* he = (const float*)d_in[2];   // (B, N, FDIM)
    float* out = (float*)d_out;
    float* scores = (float*)d_ws;              // B*N floats = 512 KB

    // Phase 1: 32 batches x 512 agent-octets = 16384 waves, 4 waves/block
    const int blocks1 = (BATCH * (NAG / 8) * 64) / 256;   // 4096
    score_kernel<<<blocks1, 256, 0, stream>>>(x, hf, he, scores);

    // Phase 2: one block per batch
    topk_gather_kernel<<<BATCH, 256, 0, stream>>>(scores, x, out);
}